// Round 1
// baseline (224.126 us; speedup 1.0000x reference)
//
#include <hip/hip_runtime.h>

typedef unsigned short u16;
typedef __attribute__((ext_vector_type(8))) short bf16x8;
typedef __attribute__((ext_vector_type(8))) unsigned short u16x8;
typedef __attribute__((ext_vector_type(4))) float f32x4;

#define DEVI static __device__ __forceinline__

DEVI u16 f2b(float f) {
  unsigned u = __builtin_bit_cast(unsigned, f);
  return (u16)((u + 0x7FFFu + ((u >> 16) & 1u)) >> 16);
}

DEVI void gload_lds16(const void* g, void* l) {
  __builtin_amdgcn_global_load_lds(
      (const __attribute__((address_space(1))) unsigned int*)g,
      (__attribute__((address_space(3))) unsigned int*)l, 16, 0, 0);
}

// ---------------- prep kernels ----------------

__global__ __launch_bounds__(256) void prep_x(const float* __restrict__ x, u16* __restrict__ xb) {
  const int n8 = 65536 * 256 / 8;
  int i = blockIdx.x * blockDim.x + threadIdx.x;
  for (; i < n8; i += gridDim.x * blockDim.x) {
    const float4* p = (const float4*)x + (size_t)i * 2;
    float4 a = p[0], b = p[1];
    u16x8 r;
    r[0] = f2b(a.x); r[1] = f2b(a.y); r[2] = f2b(a.z); r[3] = f2b(a.w);
    r[4] = f2b(b.x); r[5] = f2b(b.y); r[6] = f2b(b.z); r[7] = f2b(b.w);
    *(u16x8*)(xb + (size_t)i * 8) = r;
  }
}

// wqkvT[1536][256]: row n<512 -> Wq[:,n]*0.125 ; 512..1023 -> Wk ; 1024.. -> Wv
// woT[256][512]: row n -> Wo[:,n] ;  bqkv[1536] = concat(bq*0.125, bk, bv)
__global__ __launch_bounds__(256) void prep_w(
    const float* __restrict__ Wq, const float* __restrict__ Wk,
    const float* __restrict__ Wv, const float* __restrict__ Wo,
    const float* __restrict__ bq, const float* __restrict__ bk, const float* __restrict__ bv,
    u16* __restrict__ wqkvT, u16* __restrict__ woT, float* __restrict__ bqkv) {
  const int NW1 = 1536 * 256, NW2 = 256 * 512;
  const int total = NW1 + NW2 + 1536;
  int i = blockIdx.x * blockDim.x + threadIdx.x;
  for (; i < total; i += gridDim.x * blockDim.x) {
    if (i < NW1) {
      int nn = i >> 8, kk = i & 255;
      float v;
      if (nn < 512)       v = Wq[kk * 512 + nn] * 0.125f;
      else if (nn < 1024) v = Wk[kk * 512 + (nn - 512)];
      else                v = Wv[kk * 512 + (nn - 1024)];
      wqkvT[i] = f2b(v);
    } else if (i < NW1 + NW2) {
      int j = i - NW1;
      int nn = j >> 9, kk = j & 511;
      woT[j] = f2b(Wo[kk * 256 + nn]);
    } else {
      int j = i - NW1 - NW2;
      bqkv[j] = (j < 512) ? bq[j] * 0.125f : (j < 1024 ? bk[j - 512] : bv[j - 1024]);
    }
  }
}

// ---------------- GEMM: C[M,N] = A[M,K](bf16) * Bt[N,K]^T(bf16) + bias ----------------
// 256x256 tile, BK=64, NOW 16 waves (4M x 4N, each 64x64 out) @ 1024 threads:
// acc shrinks 128->64 regs/lane so total unified VGPR <=128 -> 4 waves/SIMD (2x occupancy
// vs the old 8-wave/128x64 layout whose 128 acc regs pinned it at 2 waves/SIMD).
// Double-buffered (128 KiB LDS) with COUNTED vmcnt: raw s_barrier + s_waitcnt vmcnt(4)
// keeps the 4 prefetch loads in flight across the barrier (T4); drain 0 only at last step.
// LDS swizzle (both-sides, rule #21): 16B-slot index ^= (row&7), applied to the per-lane
// GLOBAL source of global_load_lds (dest linear) and to the ds_read address.
// XCD-bijective block swizzle (grid % 8 == 0).

template <int KK, bool OUT_BF16>
__global__ __launch_bounds__(1024) void gemm256(
    const u16* __restrict__ A, const u16* __restrict__ Bt,
    const float* __restrict__ bias, void* __restrict__ Cv, int N) {
  constexpr int NT = KK / 64;
  __shared__ u16 smem[65536];  // 2 x [A 256x64 | B 256x64] bf16 = 128 KiB
  const int tid = threadIdx.x;
  const int lane = tid & 63, wid = tid >> 6;   // wid 0..15
  const int nTn = N >> 8;
  const int qx = gridDim.x >> 3;
  const int wg = (blockIdx.x & 7) * qx + (blockIdx.x >> 3);
  const long m0 = (long)(wg / nTn) * 256;
  const long n0 = (long)(wg % nTn) * 256;
  const int wr = wid >> 2, wc = wid & 3;       // 4x4 waves, each 64x64 out
  const int hi = lane >> 4, lo = lane & 15;
  const u16* Ab = A + m0 * KK;
  const u16* Bb = Bt + n0 * KK;
  const int srow_ = tid >> 3;  // 0..127: row within a 128-row staging round
  const int schunk = tid & 7;  // 16B chunk within row

  f32x4 acc[4][4];
#pragma unroll
  for (int mi = 0; mi < 4; ++mi)
#pragma unroll
    for (int ni = 0; ni < 4; ++ni) acc[mi][ni] = f32x4{0.f, 0.f, 0.f, 0.f};

  auto stage = [&](int t) {
    u16* base = &smem[(t & 1) * 32768];
    const int kt = t * 64;
#pragma unroll
    for (int j = 0; j < 2; ++j) {
      int row = j * 128 + srow_;
      int colE = (schunk ^ (row & 7)) << 3;  // inverse-swizzled global source
      gload_lds16(Ab + (long)row * KK + kt + colE, &base[(j * 1024 + tid) * 8]);
    }
#pragma unroll
    for (int j = 0; j < 2; ++j) {
      int row = j * 128 + srow_;
      int colE = (schunk ^ (row & 7)) << 3;
      gload_lds16(Bb + (long)row * KK + kt + colE, &base[16384 + (j * 1024 + tid) * 8]);
    }
  };

  stage(0);
#pragma unroll
  for (int t = 0; t < NT; ++t) {
    if (t + 1 < NT) {
      stage(t + 1);
      asm volatile("s_waitcnt vmcnt(4)" ::: "memory");  // batch t done; batch t+1 in flight
    } else {
      asm volatile("s_waitcnt vmcnt(0)" ::: "memory");
    }
    __builtin_amdgcn_sched_barrier(0);
    __builtin_amdgcn_s_barrier();
    const u16* aB = &smem[(t & 1) * 32768];
    const u16* bB = aB + 16384;
#pragma unroll
    for (int ks = 0; ks < 2; ++ks) {
      const int slot = ((hi + ks * 4) ^ (lo & 7)) << 3;  // swizzled k-chunk
      bf16x8 af[4], bfr[4];
#pragma unroll
      for (int mi = 0; mi < 4; ++mi)
        af[mi] = *(const bf16x8*)&aB[(wr * 64 + mi * 16 + lo) * 64 + slot];
#pragma unroll
      for (int ni = 0; ni < 4; ++ni)
        bfr[ni] = *(const bf16x8*)&bB[(wc * 64 + ni * 16 + lo) * 64 + slot];
#pragma unroll
      for (int mi = 0; mi < 4; ++mi)
#pragma unroll
        for (int ni = 0; ni < 4; ++ni)
          acc[mi][ni] = __builtin_amdgcn_mfma_f32_16x16x32_bf16(af[mi], bfr[ni], acc[mi][ni], 0, 0, 0);
    }
    __builtin_amdgcn_sched_barrier(0);
    __builtin_amdgcn_s_barrier();
  }

  float bb[4];
#pragma unroll
  for (int ni = 0; ni < 4; ++ni) bb[ni] = bias[n0 + wc * 64 + ni * 16 + lo];

  if (OUT_BF16) {
    // single-pass epilogue: full 256x256 bf16 tile = exactly 128 KiB smem.
    // chunk-XOR swizzle (chunk ^= (row>>2)&7) keeps the 4-row-strided lane writes 2-way (free).
    u16* Cg = (u16*)Cv;
#pragma unroll
    for (int mi = 0; mi < 4; ++mi)
#pragma unroll
      for (int ni = 0; ni < 4; ++ni) {
#pragma unroll
        for (int j = 0; j < 4; ++j) {
          int row = wr * 64 + mi * 16 + hi * 4 + j;
          int chunk = (wc * 8 + ni * 2 + (lo >> 3)) ^ ((row >> 2) & 7);
          smem[row * 256 + chunk * 8 + (lo & 7)] = f2b(acc[mi][ni][j] + bb[ni]);
        }
      }
    __syncthreads();
#pragma unroll
    for (int it = 0; it < 8; ++it) {
      int idx = it * 1024 + tid;
      int row = idx >> 5, c = idx & 31;
      int cs = c ^ ((row >> 2) & 7);
      *(u16x8*)(Cg + (m0 + row) * N + n0 + c * 8) = *(const u16x8*)&smem[row * 256 + cs * 8];
    }
  } else {
    float* Cg = (float*)Cv;
#pragma unroll
    for (int mi = 0; mi < 4; ++mi)
#pragma unroll
      for (int ni = 0; ni < 4; ++ni) {
        long cg = n0 + wc * 64 + ni * 16 + lo;
#pragma unroll
        for (int j = 0; j < 4; ++j)
          Cg[(m0 + wr * 64 + mi * 16 + hi * 4 + j) * N + cg] = acc[mi][ni][j] + bb[ni];
      }
  }
}

// ---------------- axial attention ----------------
// one block (4 waves) per (b,w,head); token row = (b*128+y)*128 + w.
// LDS 48 KB: [qld 16K | kld 16K | vt 16K], P (32K) aliases qld+kld after QK^T.

__global__ __launch_bounds__(256) void attn_axial(const u16* __restrict__ qkv,
                                                  u16* __restrict__ ao) {
  __shared__ u16 smem[24576];
  u16* qld = smem;               // [128][64]
  u16* kld = smem + 8192;        // [128][64]
  u16* vt  = smem + 16384;       // [64][128]  (vt[dh][y])
  u16* pld = smem;               // alias: per-wave P[32][128]

  const int g = blockIdx.x;
  const int n = g & 7, w = (g >> 3) & 127, b = g >> 10;
  const int tid = threadIdx.x, lane = tid & 63, wid = tid >> 6;
  const size_t ystr = (size_t)128 * 1536;
  const size_t base = (size_t)(b * 16384 + w) * 1536;
  const size_t bq_ = base + n * 64;
  const size_t bk_ = base + 512 + n * 64;
  const size_t bv_ = base + 1024 + n * 64;
  const int srow = lane >> 3, sc = lane & 7;
  const int hi = lane >> 4, lo = lane & 15;

#pragma unroll
  for (int j = 0; j < 4; ++j) {
    int y = wid * 32 + j * 8 + srow;
    gload_lds16(qkv + bq_ + (size_t)y * ystr + sc * 8, &qld[(wid * 32 + j * 8) * 64]);
    gload_lds16(qkv + bk_ + (size_t)y * ystr + sc * 8, &kld[(wid * 32 + j * 8) * 64]);
  }
  {
    const int h2 = tid >> 6;
    const int yp = (tid & 63) * 2;
    const u16* g0 = qkv + bv_ + (size_t)yp * ystr + h2 * 16;
    u16x8 a0 = *(const u16x8*)g0;
    u16x8 a1 = *(const u16x8*)(g0 + 8);
    u16x8 c0 = *(const u16x8*)(g0 + ystr);
    u16x8 c1 = *(const u16x8*)(g0 + ystr + 8);
    unsigned* vt32 = (unsigned*)vt;
#pragma unroll
    for (int e = 0; e < 8; ++e) {
      vt32[(h2 * 16 + e) * 64 + (yp >> 1)]     = (unsigned)a0[e] | ((unsigned)c0[e] << 16);
      vt32[(h2 * 16 + 8 + e) * 64 + (yp >> 1)] = (unsigned)a1[e] | ((unsigned)c1[e] << 16);
    }
  }
  __syncthreads();

  f32x4 s[2][8];
#pragma unroll
  for (int mi = 0; mi < 2; ++mi)
#pragma unroll
    for (int ni = 0; ni < 8; ++ni) s[mi][ni] = f32x4{0.f, 0.f, 0.f, 0.f};
#pragma unroll
  for (int ks = 0; ks < 2; ++ks) {
    bf16x8 aq[2];
#pragma unroll
    for (int mi = 0; mi < 2; ++mi)
      aq[mi] = *(const bf16x8*)&qld[(wid * 32 + mi * 16 + lo) * 64 + hi * 8 + ks * 32];
#pragma unroll
    for (int ni = 0; ni < 8; ++ni) {
      bf16x8 bk2 = *(const bf16x8*)&kld[(ni * 16 + lo) * 64 + hi * 8 + ks * 32];
#pragma unroll
      for (int mi = 0; mi < 2; ++mi)
        s[mi][ni] = __builtin_amdgcn_mfma_f32_16x16x32_bf16(aq[mi], bk2, s[mi][ni], 0, 0, 0);
    }
  }
  __syncthreads();  // qld/kld dead; P may overwrite

  float rinv[2][4];
  u16* pw = &pld[wid * 32 * 128];
#pragma unroll
  for (int mi = 0; mi < 2; ++mi) {
#pragma unroll
    for (int j = 0; j < 4; ++j) {
      float m = s[mi][0][j];
#pragma unroll
      for (int ni = 1; ni < 8; ++ni) m = fmaxf(m, s[mi][ni][j]);
#pragma unroll
      for (int d = 1; d < 16; d <<= 1) m = fmaxf(m, __shfl_xor(m, d, 64));
      float sum = 0.f;
#pragma unroll
      for (int ni = 0; ni < 8; ++ni) {
        float e = exp2f((s[mi][ni][j] - m) * 1.44269504f);
        s[mi][ni][j] = e;
        sum += e;
      }
#pragma unroll
      for (int d = 1; d < 16; d <<= 1) sum += __shfl_xor(sum, d, 64);
      rinv[mi][j] = 1.f / sum;
      const int q = mi * 16 + hi * 4 + j;
#pragma unroll
      for (int ni = 0; ni < 8; ++ni)
        pw[q * 128 + ni * 16 + lo] = f2b(s[mi][ni][j]);
    }
  }

  f32x4 o[2][4];
#pragma unroll
  for (int mi = 0; mi < 2; ++mi)
#pragma unroll
    for (int ni = 0; ni < 4; ++ni) o[mi][ni] = f32x4{0.f, 0.f, 0.f, 0.f};
#pragma unroll
  for (int ks = 0; ks < 4; ++ks) {
    bf16x8 ap[2];
#pragma unroll
    for (int mi = 0; mi < 2; ++mi)
      ap[mi] = *(const bf16x8*)&pw[(mi * 16 + lo) * 128 + hi * 8 + ks * 32];
#pragma unroll
    for (int ni = 0; ni < 4; ++ni) {
      bf16x8 bv2 = *(const bf16x8*)&vt[(ni * 16 + lo) * 128 + hi * 8 + ks * 32];
#pragma unroll
      for (int mi = 0; mi < 2; ++mi)
        o[mi][ni] = __builtin_amdgcn_mfma_f32_16x16x32_bf16(ap[mi], bv2, o[mi][ni], 0, 0, 0);
    }
  }

#pragma unroll
  for (int mi = 0; mi < 2; ++mi)
#pragma unroll
    for (int j = 0; j < 4; ++j) {
      const int q = wid * 32 + mi * 16 + hi * 4 + j;
      const size_t obase = ((size_t)(b * 16384 + q * 128 + w)) * 512 + (size_t)n * 64;
#pragma unroll
      for (int ni = 0; ni < 4; ++ni)
        ao[obase + ni * 16 + lo] = f2b(o[mi][ni][j] * rinv[mi][j]);
    }
}

// ---------------- launch ----------------
// ws: qkv [0,192MiB) | xb [192,224) | weights [224,~226)
// ao (bf16, 64 MB) lives IN d_out; gemm2 runs in-place (each block reads only its
// own 256 rows as bf16 before overwriting them as f32 -> race-free, deterministic).

extern "C" void kernel_launch(void* const* d_in, const int* in_sizes, int n_in,
                              void* d_out, int out_size, void* d_ws, size_t ws_size,
                              hipStream_t stream) {
  (void)in_sizes; (void)n_in; (void)out_size; (void)ws_size;
  const float* x  = (const float*)d_in[0];
  const float* Wq = (const float*)d_in[1];
  const float* bq = (const float*)d_in[2];
  const float* Wk = (const float*)d_in[3];
  const float* bk = (const float*)d_in[4];
  const float* Wv = (const float*)d_in[5];
  const float* bv = (const float*)d_in[6];
  const float* Wo = (const float*)d_in[7];
  const float* bo = (const float*)d_in[8];
  float* out = (float*)d_out;

  char* ws = (char*)d_ws;
  const size_t MiB = (size_t)1 << 20;
  u16* qkv   = (u16*)ws;
  u16* xb    = (u16*)(ws + 192 * MiB);
  u16* wqkvT = (u16*)(ws + 224 * MiB);
  u16* woT   = wqkvT + 1536 * 256;
  float* bqkv = (float*)(woT + 256 * 512);

  prep_x<<<2048, 256, 0, stream>>>(x, xb);
  prep_w<<<512, 256, 0, stream>>>(Wq, Wk, Wv, Wo, bq, bk, bv, wqkvT, woT, bqkv);

  gemm256<256, true><<<1536, 1024, 0, stream>>>(xb, wqkvT, bqkv, qkv, 1536);
  attn_axial<<<4096, 256, 0, stream>>>(qkv, (u16*)out);
  gemm256<512, false><<<256, 1024, 0, stream>>>((const u16*)out, woT, bo, out, 256);
}